// Round 1
// baseline (9146.020 us; speedup 1.0000x reference)
//
#include <hip/hip_runtime.h>
#include <hip/hip_bf16.h>
#include <math.h>

// Problem constants
#define BB 64
#define TT 512
#define II 256
#define HH 512
#define GG 2048   // 4H
#define NBLK 128  // 32 col-slices * 4 b-tiles
#define HPAD 520  // h row pad (bf16 elems): 260 dwords -> 2-way bank alias (free), keeps 16B align
#define XPAD 264  // x / W_ih row pad

typedef unsigned short u16;
typedef __attribute__((ext_vector_type(4))) short short4v;
typedef __attribute__((ext_vector_type(8))) short short8v;
typedef __attribute__((ext_vector_type(4))) float f32x4;

__device__ __forceinline__ u16 f2bf(float f) {
    unsigned u = __float_as_uint(f);
    unsigned r = (u + 0x7fff + ((u >> 16) & 1)) >> 16;  // RNE
    return (u16)r;
}
__device__ __forceinline__ float bf2f(u16 h) {
    return __uint_as_float(((unsigned)h) << 16);
}
__device__ __forceinline__ float sigf(float v) {
    return 1.f / (1.f + __expf(-v));   // v << 0: exp->inf -> 0, safe
}
__device__ __forceinline__ float tanh_s(float v) {
    float a = fabsf(v);
    float e = __expf(2.f * a);         // a large: e->inf -> r->1, safe
    float r = 1.f - 2.f / (e + 1.f);
    return copysignf(r, v);
}

__global__ void __launch_bounds__(64, 1) slstm_kernel(
    const float* __restrict__ x, const float* __restrict__ wih,
    const float* __restrict__ whh, const float* __restrict__ bias,
    float* __restrict__ out, unsigned* __restrict__ arr,
    u16* __restrict__ hbuf /* [2 parity][2 hi/lo][BB][HH] bf16 */)
{
    __shared__ u16 lds_h[2][16 * HPAD];  // [hi/lo][16 b rows][512 k]
    __shared__ u16 lds_x[16 * XPAD];     // [16 b rows][256 k]
    __shared__ u16 lds_w[64 * XPAD];     // W_ih^T: [64 gate-cols][256 k]

    const int l  = threadIdx.x;          // lane 0..63 (1 wave)
    const int bt = blockIdx.x & 3;       // b-tile
    const int js = blockIdx.x >> 2;      // h-col slice
    const int b0 = bt * 16, j0 = js * 16;
    const int c  = l & 15, kq = l >> 4;  // frag col / k-quad

    // ---- preload W_hh B-fragments into registers (bf16), resident all run ----
    // B-frag for tile q, k-step s: lane l holds W_hh[32s+8*kq+j][q*512+j0+c], j=0..7
    short8v wb[4][16];
#pragma unroll
    for (int q = 0; q < 4; ++q) {
        const float* wcol = whh + (q * 512 + j0 + c);
#pragma unroll
        for (int s = 0; s < 16; ++s) {
            short8v v;
#pragma unroll
            for (int j = 0; j < 8; ++j) {
                int k = 32 * s + 8 * kq + j;
                v[j] = (short)f2bf(wcol[(size_t)k * GG]);
            }
            wb[q][s] = v;
        }
    }

    // ---- W_ih slice -> LDS, transposed to [gate-col][k] for B-frag reads ----
    for (int q = 0; q < 4; ++q) {
        for (int kk = 0; kk < 64; ++kk) {
            int k = kk * 4 + kq;
            float v = wih[(size_t)k * GG + q * 512 + j0 + c];
            lds_w[(q * 16 + c) * XPAD + k] = f2bf(v);
        }
    }

    float bq[4];
#pragma unroll
    for (int q = 0; q < 4; ++q) bq[q] = bias[q * 512 + j0 + c];

    float cst[4] = {0.f, 0.f, 0.f, 0.f};   // c-state in C/D frag layout
    __syncthreads();

    for (int t = 0; t < TT; ++t) {
        // ---- stage x tile: x[b0+r][t][0..255] -> bf16 LDS (16 rows, 1 row/iter) ----
#pragma unroll 4
        for (int r = 0; r < 16; ++r) {
            float4 v = *(const float4*)(x + ((size_t)(b0 + r) * TT + t) * II + 4 * l);
            short4v p;
            p[0] = (short)f2bf(v.x); p[1] = (short)f2bf(v.y);
            p[2] = (short)f2bf(v.z); p[3] = (short)f2bf(v.w);
            *(short4v*)&lds_x[r * XPAD + 4 * l] = p;
        }
        __syncthreads();

        // ---- xp = bias + x @ W_ih  (overlaps other blocks finishing step t-1) ----
        f32x4 acc[4];
#pragma unroll
        for (int q = 0; q < 4; ++q) acc[q] = (f32x4){bq[q], bq[q], bq[q], bq[q]};
#pragma unroll
        for (int s = 0; s < 8; ++s) {
            short8v a = *(const short8v*)&lds_x[c * XPAD + 32 * s + 8 * kq];
#pragma unroll
            for (int q = 0; q < 4; ++q) {
                short8v b = *(const short8v*)&lds_w[(q * 16 + c) * XPAD + 32 * s + 8 * kq];
                acc[q] = __builtin_amdgcn_mfma_f32_16x16x32_bf16(a, b, acc[q], 0, 0, 0);
            }
        }

        // ---- wait for h_{t-1} (all 128 producers) ----
        if (t > 0) {
            while (__hip_atomic_load(arr + (t - 1), __ATOMIC_RELAXED,
                                     __HIP_MEMORY_SCOPE_AGENT) < NBLK)
                __builtin_amdgcn_s_sleep(1);
            (void)__hip_atomic_load(arr + (t - 1), __ATOMIC_ACQUIRE,
                                    __HIP_MEMORY_SCOPE_AGENT);
        }

        // ---- stage h tile (hi & lo bf16), rows b0..b0+15 ----
        const int rp = (t - 1) & 1;   // t=0 -> parity 1 (zeroed by memset)
#pragma unroll
        for (int hl = 0; hl < 2; ++hl) {
            const u16* src = hbuf + ((size_t)rp * 2 + hl) * BB * HH + (size_t)b0 * HH;
            u16* dst = lds_h[hl];
#pragma unroll 4
            for (int i = 0; i < 16; ++i) {
                int ch = i * 64 + l;             // 1024 chunks of 8 bf16
                int r = ch >> 6, k0 = (ch & 63) * 8;
                short8v v = *(const short8v*)(src + r * HH + k0);
                *(short8v*)&dst[r * HPAD + k0] = v;
            }
        }
        __syncthreads();

        // ---- gates += (h_hi + h_lo) @ W_hh   (compensated bf16 product) ----
#pragma unroll
        for (int s = 0; s < 16; ++s) {
            short8v ah = *(const short8v*)&lds_h[0][c * HPAD + 32 * s + 8 * kq];
            short8v al = *(const short8v*)&lds_h[1][c * HPAD + 32 * s + 8 * kq];
#pragma unroll
            for (int q = 0; q < 4; ++q)
                acc[q] = __builtin_amdgcn_mfma_f32_16x16x32_bf16(ah, wb[q][s], acc[q], 0, 0, 0);
#pragma unroll
            for (int q = 0; q < 4; ++q)
                acc[q] = __builtin_amdgcn_mfma_f32_16x16x32_bf16(al, wb[q][s], acc[q], 0, 0, 0);
        }

        // ---- epilogue: activations, c update, writes ----
        // D layout: col = j0 + (lane&15), row b = b0 + (lane>>4)*4 + reg  [m89/m91]
        const int wp = t & 1;
        u16* hdst_hi = hbuf + ((size_t)wp * 2 + 0) * BB * HH;
        u16* hdst_lo = hbuf + ((size_t)wp * 2 + 1) * BB * HH;
        const int j = j0 + c;
#pragma unroll
        for (int rg = 0; rg < 4; ++rg) {
            int b = b0 + kq * 4 + rg;
            float ig = sigf(acc[0][rg]);
            float fg = sigf(acc[1][rg]);
            float cg = tanh_s(acc[2][rg]);
            float og = acc[3][rg];            // NOTE: reference applies NO sigmoid to og
            float cy = fg * cst[rg] + ig * cg;
            cst[rg] = cy;
            float hy = og * tanh_s(cy) + og;  // hy = og*tanh(cy) + og (reference quirk)
            out[((size_t)b * TT + t) * HH + j] = hy;
            u16 hi = f2bf(hy);
            float lo = hy - bf2f(hi);
            __hip_atomic_store(&hdst_hi[(size_t)b * HH + j], hi,
                               __ATOMIC_RELAXED, __HIP_MEMORY_SCOPE_AGENT);
            __hip_atomic_store(&hdst_lo[(size_t)b * HH + j], f2bf(lo),
                               __ATOMIC_RELAXED, __HIP_MEMORY_SCOPE_AGENT);
        }
        __threadfence();                       // release h stores before arrival
        if (l == 0) atomicAdd(arr + t, 1u);    // device-scope arrival
    }
}

extern "C" void kernel_launch(void* const* d_in, const int* in_sizes, int n_in,
                              void* d_out, int out_size, void* d_ws, size_t ws_size,
                              hipStream_t stream) {
    const float* x    = (const float*)d_in[0];
    const float* wih  = (const float*)d_in[1];
    const float* whh  = (const float*)d_in[2];
    const float* bias = (const float*)d_in[3];
    float* out = (float*)d_out;

    // ws layout: [0,2KB) arrival counters; [4KB, 4KB+512KB) h ping-pong (hi/lo bf16)
    unsigned* arr = (unsigned*)d_ws;
    u16* hbuf = (u16*)((char*)d_ws + 4096);
    size_t clear = 4096 + (size_t)2 * 2 * BB * HH * sizeof(u16);
    hipMemsetAsync(d_ws, 0, clear, stream);   // counters=0, h_{-1}=0 (every call)

    hipLaunchKernelGGL(slstm_kernel, dim3(NBLK), dim3(64), 0, stream,
                       x, wih, whh, bias, out, arr, hbuf);
}